// Round 1
// 629.242 us; speedup vs baseline: 1.1647x; 1.1647x over previous
//
#include <hip/hip_runtime.h>
#include <stdint.h>

// B=4, C=192, H=W=224, WS=8, NH=6, hd=32, SHIFT=4. I/O fp32; internal bf16 MFMA.
#define HHW   224
#define CCH   192
#define SHIFT 4
#define NWIN  3136           // 4 * 28 * 28
#define NTOK  200704         // NWIN * 64
#define QN    38535168ull    // NWIN*6*64*32 elements per Q/K/VT tensor (bf16)

typedef __attribute__((ext_vector_type(8))) short bf16x8;   // MFMA A/B frag
typedef __attribute__((ext_vector_type(4))) float f32x4;    // MFMA C/D frag

__device__ __forceinline__ ushort f2bf(float f) {
    union { float f; uint32_t i; } v; v.f = f;
    uint32_t u = v.i;
    return (ushort)((u + 0x7FFFu + ((u >> 16) & 1u)) >> 16);  // RNE
}

// ---------------------------------------------------------------------------
// prep_w: weights fp32 [o][c] -> bf16 pre-swizzled linear LDS image, once.
// Chunk ch = rows [ch*96, ch*96+96). Image[rg][p*8+j] = w[rg][(p^(rg&7))*8+j]
// (rg&7 == (rg%96)&7 since 96%8==0). gemm stages this image linearly via
// global_load_lds and reads slot p = s_log ^ (l16&7)  -> XOR cancels ->
// logical weight, with conflict-free b128 reads (each 8-lane group covers
// all 32 banks exactly once).
// ---------------------------------------------------------------------------
__global__ __launch_bounds__(256) void prep_w(const float* __restrict__ w,
                                              ushort* __restrict__ wo, int nrow)
{
    int idx = blockIdx.x * 256 + threadIdx.x;
    if (idx >= nrow * 24) return;
    int rg = idx / 24, p = idx % 24;
    int s = p ^ (rg & 7);                    // XOR only touches low 3 bits
    const float* src = w + (size_t)rg * 192 + s * 8;
    float4 a = *(const float4*)src;
    float4 b = *(const float4*)(src + 4);
    uint4 o;
    o.x = (uint32_t)f2bf(a.x) | ((uint32_t)f2bf(a.y) << 16);
    o.y = (uint32_t)f2bf(a.z) | ((uint32_t)f2bf(a.w) << 16);
    o.z = (uint32_t)f2bf(b.x) | ((uint32_t)f2bf(b.y) << 16);
    o.w = (uint32_t)f2bf(b.z) | ((uint32_t)f2bf(b.w) << 16);
    *(uint4*)(wo + (size_t)rg * 192 + p * 8) = o;
}

// ---------------------------------------------------------------------------
// prep: x fp32 [b][c][h][w] -> X1 bf16 [p][c], p = win*64 + t, roll(+4) folded.
// SHIFT=4 guarantees every 4-pixel token run is a contiguous aligned float4
// even across the %224 wrap. LDS transpose -> fully coalesced uint4 out.
// ---------------------------------------------------------------------------
__global__ __launch_bounds__(256) void prep_x(const float* __restrict__ x,
                                              ushort* __restrict__ xo)
{
    __shared__ ushort xt[64][200];   // +8 pad
    const int win = blockIdx.x;
    const int b = win / 784, hn = (win / 28) % 28, wn = win % 28;
    const float* xb = x + (size_t)b * CCH * HHW * HHW;

    for (int u = threadIdx.x; u < CCH * 16; u += 256) {
        int c = u >> 4, r = u & 15;
        int t0 = r * 4;                       // tokens t0..t0+3: same row-of-8
        int hh = (hn * 8 + (t0 >> 3) + SHIFT) % HHW;
        int ww = (wn * 8 + (t0 & 7) + SHIFT) % HHW;   // %4==0, wrap-safe
        float4 v = *(const float4*)(xb + ((size_t)c * HHW + hh) * HHW + ww);
        xt[t0 + 0][c] = f2bf(v.x); xt[t0 + 1][c] = f2bf(v.y);
        xt[t0 + 2][c] = f2bf(v.z); xt[t0 + 3][c] = f2bf(v.w);
    }
    __syncthreads();
    ushort* xw = xo + (size_t)win * 12288;
    for (int u = threadIdx.x; u < 64 * 24; u += 256) {
        int t = u / 24, c8 = u % 24;
        *(uint4*)(xw + t * 192 + c8 * 8) = *(const uint4*)&xt[t][c8 * 8];
    }
}

// ---------------------------------------------------------------------------
// GEMM: out[o][p] = bias[o] + sum_c W[o][c] * X1[p][c].  N=128 tokens/block,
// wave owns 32 tokens (2 n-frags); B-frags loaded ONCE directly from global.
// A = pre-converted bf16 weights staged per 96-row chunk via global_load_lds
// (9 x 16B per thread, linear LDS), read back with XOR-swizzled conflict-free
// ds_read_b128. Next chunk's staging is issued before this chunk's epilogue
// so the DMA hides under epilogue VALU/stores.
// OCH=576: packed uint2 Q/K stores + V^T scatter.  OCH=192: fp32 out scatter
// with roll fold.
// ---------------------------------------------------------------------------
template<int OCH>
__global__ __launch_bounds__(256, 3) void gemm_win(
    const ushort* __restrict__ xin, const ushort* __restrict__ wbf,
    const float* __restrict__ bias,
    ushort* __restrict__ qo, ushort* __restrict__ ko, ushort* __restrict__ vto,
    float* __restrict__ dout)
{
    __shared__ ushort wc[96 * 192];  // 36864 B linear weight chunk (bf16)

    const int tid = threadIdx.x;
    const int wave = tid >> 6, lane = tid & 63;
    const int quad = lane >> 4, l16 = lane & 15;
    const int p0 = blockIdx.x * 128 + wave * 32;

    // Stage chunk 0 (async DMA, drained by the barrier below).
    #pragma unroll
    for (int it = 0; it < 9; it++) {
        int off = (it * 4 + wave) * 512;             // ushort offset, 1KB/wave/iter
        __builtin_amdgcn_global_load_lds(
            (const __attribute__((address_space(1))) void*)(wbf + off + lane * 8),
            (__attribute__((address_space(3))) void*)(&wc[off]), 16, 0, 0);
    }

    // B-frags: all 192 channels of this wave's 32 tokens, held in VGPRs.
    bf16x8 bfr[2][6];
    #pragma unroll
    for (int nt = 0; nt < 2; nt++)
        #pragma unroll
        for (int k = 0; k < 6; k++)
            bfr[nt][k] = *(const bf16x8*)(xin + (size_t)(p0 + nt * 16 + l16) * CCH + k * 32 + quad * 8);

    __syncthreads();    // vmcnt(0) drain: chunk 0 + bfr ready

    #pragma unroll
    for (int ch = 0; ch < OCH / 96; ch++) {
        f32x4 acc[6][2];
        #pragma unroll
        for (int m = 0; m < 6; m++)
            #pragma unroll
            for (int nt = 0; nt < 2; nt++) acc[m][nt] = (f32x4){0.f, 0.f, 0.f, 0.f};

        const ushort* wl = wc + (size_t)l16 * 192;
        #pragma unroll
        for (int k = 0; k < 6; k++) {
            const ushort* wk = wl + ((k * 4 + quad) ^ (l16 & 7)) * 8;
            #pragma unroll
            for (int m = 0; m < 6; m++) {
                bf16x8 afrag = *(const bf16x8*)(wk + m * 3072);
                acc[m][0] = __builtin_amdgcn_mfma_f32_16x16x32_bf16(afrag, bfr[0][k], acc[m][0], 0, 0, 0);
                acc[m][1] = __builtin_amdgcn_mfma_f32_16x16x32_bf16(afrag, bfr[1][k], acc[m][1], 0, 0, 0);
            }
        }

        // Issue next chunk's staging now; its latency hides under the epilogue.
        if (ch + 1 < OCH / 96) {
            __syncthreads();     // all waves done reading chunk ch
            const ushort* wsrc = wbf + (size_t)(ch + 1) * (96 * 192);
            #pragma unroll
            for (int it = 0; it < 9; it++) {
                int off = (it * 4 + wave) * 512;
                __builtin_amdgcn_global_load_lds(
                    (const __attribute__((address_space(1))) void*)(wsrc + off + lane * 8),
                    (__attribute__((address_space(3))) void*)(&wc[off]), 16, 0, 0);
            }
        }

        // Epilogue. D row = quad*4+rg (o dim), col = l16 (token dim).
        const int obase = ch * 96;
        #pragma unroll
        for (int m = 0; m < 6; m++) {
            const int o0 = obase + m * 16 + quad * 4;          // %4 == 0
            float4 bb = *(const float4*)(bias + o0);           // 16-lane broadcast, cached
            #pragma unroll
            for (int nt = 0; nt < 2; nt++) {
                int token = p0 + nt * 16 + l16;
                int win = token >> 6, t = token & 63;
                float f0 = acc[m][nt][0] + bb.x, f1 = acc[m][nt][1] + bb.y;
                float f2 = acc[m][nt][2] + bb.z, f3 = acc[m][nt][3] + bb.w;
                if (OCH == 576) {
                    const int s = o0 / 192;                    // uniform per (ch,m)
                    const int rem = o0 % 192;
                    const int h = rem >> 5, d0 = rem & 31;     // d0 %4 == 0
                    size_t wh = (size_t)win * 6 + h;
                    if (s == 2) {
                        vto[(wh * 32 + d0 + 0) * 64 + t] = f2bf(f0);
                        vto[(wh * 32 + d0 + 1) * 64 + t] = f2bf(f1);
                        vto[(wh * 32 + d0 + 2) * 64 + t] = f2bf(f2);
                        vto[(wh * 32 + d0 + 3) * 64 + t] = f2bf(f3);
                    } else {
                        uint2 pk;
                        pk.x = (uint32_t)f2bf(f0) | ((uint32_t)f2bf(f1) << 16);
                        pk.y = (uint32_t)f2bf(f2) | ((uint32_t)f2bf(f3) << 16);
                        ushort* dst = (s == 0 ? qo : ko) + (wh * 64 + t) * 32 + d0;
                        *(uint2*)dst = pk;
                    }
                } else {
                    int b = win / 784, hn = (win / 28) % 28, wn = win % 28;
                    int hh = (hn * 8 + (t >> 3) + SHIFT) % HHW;
                    int ww = (wn * 8 + (t & 7) + SHIFT) % HHW;
                    float* dst = dout + ((size_t)(b * CCH + o0) * HHW + hh) * HHW + ww;
                    dst[0] = f0; dst[(size_t)HHW * HHW] = f1;
                    dst[2 * (size_t)HHW * HHW] = f2; dst[3 * (size_t)HHW * HHW] = f3;
                }
            }
        }
        if (ch + 1 < OCH / 96) __syncthreads();   // staging DMA drained (vmcnt 0)
    }
}

// ---------------------------------------------------------------------------
// attn: one block = one window, 6 waves = 6 heads. QK^T -> softmax -> P via
// LDS -> PV. Output X2 bf16 [t][c] ALIASED onto the Q buffer (same per-window
// 24 KB block). Safe: all Q/K/V frag loads are issued before __syncthreads
// (which drains vmcnt(0)); X2 stores happen strictly after.
// ---------------------------------------------------------------------------
__global__ __launch_bounds__(384, 3) void attn_win(
    ushort* qx2,                                   // Q in / X2 out (aliased)
    const ushort* __restrict__ k, const ushort* __restrict__ vt)
{
    __shared__ ushort pt[6][64][72];

    const int tid = threadIdx.x;
    const int h = tid >> 6, lane = tid & 63;
    const int quad = lane >> 4, l16 = lane & 15;
    const int win = blockIdx.x;

    const ushort* qp = qx2 + (size_t)(win * 6 + h) * 2048;
    const ushort* kp = k   + (size_t)(win * 6 + h) * 2048;
    const ushort* vp = vt  + (size_t)(win * 6 + h) * 2048;

    // Hoist K and V frags (V must be loaded before the barrier for aliasing).
    bf16x8 kf[4], vf[2][2];
    #pragma unroll
    for (int nt = 0; nt < 4; nt++) kf[nt] = *(const bf16x8*)&kp[(nt * 16 + l16) * 32 + quad * 8];
    #pragma unroll
    for (int ks = 0; ks < 2; ks++)
        #pragma unroll
        for (int nt = 0; nt < 2; nt++)
            vf[ks][nt] = *(const bf16x8*)&vp[(nt * 16 + l16) * 64 + ks * 32 + quad * 8];

    f32x4 s[4][4];
    #pragma unroll
    for (int mt = 0; mt < 4; mt++) {
        bf16x8 qf = *(const bf16x8*)&qp[(mt * 16 + l16) * 32 + quad * 8];
        #pragma unroll
        for (int nt = 0; nt < 4; nt++) {
            s[mt][nt] = (f32x4){0.f, 0.f, 0.f, 0.f};
            s[mt][nt] = __builtin_amdgcn_mfma_f32_16x16x32_bf16(qf, kf[nt], s[mt][nt], 0, 0, 0);
        }
    }

    const float SC = 0.25506953149031837f;   // (1/sqrt(32)) * log2(e)
    #pragma unroll
    for (int mt = 0; mt < 4; mt++) {
        #pragma unroll
        for (int rg = 0; rg < 4; rg++) {
            float v0 = s[mt][0][rg], v1 = s[mt][1][rg], v2 = s[mt][2][rg], v3 = s[mt][3][rg];
            float mx = fmaxf(fmaxf(v0, v1), fmaxf(v2, v3));
            #pragma unroll
            for (int msk = 1; msk < 16; msk <<= 1) mx = fmaxf(mx, __shfl_xor(mx, msk, 64));
            float e0 = exp2f((v0 - mx) * SC), e1 = exp2f((v1 - mx) * SC);
            float e2 = exp2f((v2 - mx) * SC), e3 = exp2f((v3 - mx) * SC);
            float sm = (e0 + e1) + (e2 + e3);
            #pragma unroll
            for (int msk = 1; msk < 16; msk <<= 1) sm += __shfl_xor(sm, msk, 64);
            float r = __builtin_amdgcn_rcpf(sm);
            int qt = mt * 16 + quad * 4 + rg;
            pt[h][qt][ 0 + l16] = f2bf(e0 * r);
            pt[h][qt][16 + l16] = f2bf(e1 * r);
            pt[h][qt][32 + l16] = f2bf(e2 * r);
            pt[h][qt][48 + l16] = f2bf(e3 * r);
        }
    }
    __syncthreads();   // drains all global loads; X2 stores are after this

    f32x4 o[4][2];
    #pragma unroll
    for (int mt = 0; mt < 4; mt++)
        #pragma unroll
        for (int nt = 0; nt < 2; nt++) o[mt][nt] = (f32x4){0.f, 0.f, 0.f, 0.f};
    #pragma unroll
    for (int ks = 0; ks < 2; ks++)
        #pragma unroll
        for (int mt = 0; mt < 4; mt++) {
            bf16x8 pf = *(const bf16x8*)&pt[h][mt * 16 + l16][ks * 32 + quad * 8];
            #pragma unroll
            for (int nt = 0; nt < 2; nt++)
                o[mt][nt] = __builtin_amdgcn_mfma_f32_16x16x32_bf16(pf, vf[ks][nt], o[mt][nt], 0, 0, 0);
        }

    // X2[t][c] bf16, c = h*32 + nt*16 + l16 (lane-contiguous 32B segments).
    ushort* x2 = qx2 + (size_t)win * 12288;
    #pragma unroll
    for (int mt = 0; mt < 4; mt++)
        #pragma unroll
        for (int nt = 0; nt < 2; nt++)
            #pragma unroll
            for (int rg = 0; rg < 4; rg++) {
                int qt = mt * 16 + quad * 4 + rg;
                x2[qt * CCH + h * 32 + nt * 16 + l16] = f2bf(o[mt][nt][rg]);
            }
}

extern "C" void kernel_launch(void* const* d_in, const int* in_sizes, int n_in,
                              void* d_out, int out_size, void* d_ws, size_t ws_size,
                              hipStream_t stream) {
    const float* x      = (const float*)d_in[0];
    const float* w_qkv  = (const float*)d_in[1];
    const float* b_qkv  = (const float*)d_in[2];
    const float* w_proj = (const float*)d_in[3];
    const float* b_proj = (const float*)d_in[4];
    float* out = (float*)d_out;
    ushort* ws = (ushort*)d_ws;

    ushort* X1 = (ushort*)d_out;       // 77 MB bf16 region inside d_out (154 MB)
    ushort* WQ = (ushort*)d_out + QN;  // bf16 qkv weights in d_out's spare half
                                       // (dead until final gemm writes out)
    ushort* Q  = ws;                   // [win][h][64][32] bf16; becomes X2 [win][t][c]
    ushort* K  = ws + QN;
    ushort* VT = ws + 2 * QN;          // [win][h][32][64] bf16 (ws total 231 MB)
    ushort* WP = VT;                   // bf16 proj weights reuse VT (dead post-attn)

    prep_w       <<<54, 256, 0, stream>>>(w_qkv, WQ, 576);
    prep_x       <<<NWIN, 256, 0, stream>>>(x, X1);
    gemm_win<576><<<NTOK / 128, 256, 0, stream>>>(X1, WQ, b_qkv, Q, K, VT, nullptr);
    attn_win     <<<NWIN, 384, 0, stream>>>(Q, K, VT);
    prep_w       <<<18, 256, 0, stream>>>(w_proj, WP, 192);
    gemm_win<192><<<NTOK / 128, 256, 0, stream>>>(Q, WP, b_proj, nullptr, nullptr, nullptr, out);
}

// Round 2
// 564.753 us; speedup vs baseline: 1.2977x; 1.1142x over previous
//
#include <hip/hip_runtime.h>
#include <stdint.h>

// B=4, C=192, H=W=224, WS=8, NH=6, hd=32, SHIFT=4. I/O fp32; internal bf16 MFMA.
#define HHW   224
#define CCH   192
#define SHIFT 4
#define NWIN  3136           // 4 * 28 * 28
#define NTOK  200704         // NWIN * 64
#define QN    38535168ull    // NWIN*6*64*32 elements per Q/K/VT tensor (bf16)

typedef __attribute__((ext_vector_type(8))) short bf16x8;   // MFMA A/B frag
typedef __attribute__((ext_vector_type(4))) float f32x4;    // MFMA C/D frag

__device__ __forceinline__ ushort f2bf(float f) {
    union { float f; uint32_t i; } v; v.f = f;
    uint32_t u = v.i;
    return (ushort)((u + 0x7FFFu + ((u >> 16) & 1u)) >> 16);  // RNE
}
__device__ __forceinline__ uint32_t pk2(float a, float b) {
    return (uint32_t)f2bf(a) | ((uint32_t)f2bf(b) << 16);
}

// ---------------------------------------------------------------------------
// prep_w: weights fp32 [o][c] -> bf16 pre-swizzled linear image, once.
// Image[rg][p*8+j] = w[rg][(p^(rg&7))*8+j]; gemm stages linearly via
// global_load_lds and reads slot p = s_log ^ (l16&7) -> XOR cancels ->
// conflict-free b128 reads.
// ---------------------------------------------------------------------------
__global__ __launch_bounds__(256) void prep_w(const float* __restrict__ w,
                                              ushort* __restrict__ wo, int nrow)
{
    int idx = blockIdx.x * 256 + threadIdx.x;
    if (idx >= nrow * 24) return;
    int rg = idx / 24, p = idx % 24;
    int s = p ^ (rg & 7);                    // XOR only touches low 3 bits
    const float* src = w + (size_t)rg * 192 + s * 8;
    float4 a = *(const float4*)src;
    float4 b = *(const float4*)(src + 4);
    uint4 o;
    o.x = pk2(a.x, a.y); o.y = pk2(a.z, a.w);
    o.z = pk2(b.x, b.y); o.w = pk2(b.z, b.w);
    *(uint4*)(wo + (size_t)rg * 192 + p * 8) = o;
}

// ---------------------------------------------------------------------------
// prep_x: x fp32 [b][c][h][w] -> X1 bf16 [win][oct][t][8ch], roll(+4) folded.
// Block = (b, hn, channel-octet). Reads FULL 896B image rows (the roll makes
// each output row exactly one rotated source row -> every 64B line consumed
// once, zero over-fetch). Register transpose: thread holds 4 px x 8 ch ->
// b128 LDS writes into XOR-swizzled [p][8ch] tile (slot = p ^ ((p>>3)&7);
// uniform 8-slot distribution for both write and read waves -> conflict-free).
// Output: per (window, octet) a 1KB fully-contiguous burst.
// ---------------------------------------------------------------------------
__global__ __launch_bounds__(256) void prep_x(const float* __restrict__ x,
                                              ushort* __restrict__ xo)
{
    __shared__ ushort lt[1792 * 8];          // [p][8ch], 16B rows, swizzled
    const int blk = blockIdx.x;              // ((b*28 + hn)*24 + oct)
    const int oct = blk % 24;
    const int bh  = blk / 24;                // b*28 + hn
    const int hn  = bh % 28;
    const float* xb = x + ((size_t)(bh / 28) * CCH + oct * 8) * (HHW * HHW);

    // Read phase: task u = pixel-quad index (r = u/56, 4-col group q = u%56).
    for (int u = threadIdx.x; u < 448; u += 256) {
        int r = u / 56, q = u % 56;
        int hh = (hn * 8 + r + SHIFT) % HHW;
        int ww = (q * 4 + SHIFT) % HHW;      // %4==0, wrap lands on float4 bound
        const float* src = xb + (size_t)hh * HHW + ww;
        float4 v[8];
        #pragma unroll
        for (int c = 0; c < 8; c++)
            v[c] = *(const float4*)(src + (size_t)c * (HHW * HHW));
        #pragma unroll
        for (int i = 0; i < 4; i++) {
            int p = u * 4 + i;               // = r*224 + q*4 + i
            int sw = p ^ ((p >> 3) & 7);
            uint4 o;
            o.x = pk2(((const float*)&v[0])[i], ((const float*)&v[1])[i]);
            o.y = pk2(((const float*)&v[2])[i], ((const float*)&v[3])[i]);
            o.z = pk2(((const float*)&v[4])[i], ((const float*)&v[5])[i]);
            o.w = pk2(((const float*)&v[6])[i], ((const float*)&v[7])[i]);
            *(uint4*)&lt[sw * 8] = o;
        }
    }
    __syncthreads();

    // Write phase: per window wn, token t -> 16B; lanes t consecutive -> 1KB bursts.
    for (int u = threadIdx.x; u < 1792; u += 256) {
        int wn = u >> 6, t = u & 63;
        int p = (t >> 3) * 224 + wn * 8 + (t & 7);
        int sw = p ^ ((p >> 3) & 7);
        *(uint4*)(xo + (size_t)(bh * 28 + wn) * 12288 + oct * 512 + t * 8) =
            *(const uint4*)&lt[sw * 8];
    }
}

// ---------------------------------------------------------------------------
// GEMM: out[o][p] = bias[o] + sum_c W[o][c] * X1[p][c].  N=128 tokens/block,
// wave owns 32 tokens (2 n-frags); B-frags loaded ONCE directly from global.
// OCH=576 input layout: [win][oct][t][8ch] (fully coalesced 16B/lane).
// OCH=192 input layout: [t][c] token rows (X2 from attn).
// A = pre-converted bf16 weights staged per 96-row chunk via global_load_lds
// (9 x 16B per thread, linear LDS), read back with XOR-swizzled conflict-free
// ds_read_b128. Next chunk's staging is issued before this chunk's epilogue.
// ---------------------------------------------------------------------------
template<int OCH>
__global__ __launch_bounds__(256, 3) void gemm_win(
    const ushort* __restrict__ xin, const ushort* __restrict__ wbf,
    const float* __restrict__ bias,
    ushort* __restrict__ qo, ushort* __restrict__ ko, ushort* __restrict__ vto,
    float* __restrict__ dout)
{
    __shared__ ushort wc[96 * 192];  // 36864 B linear weight chunk (bf16)

    const int tid = threadIdx.x;
    const int wave = tid >> 6, lane = tid & 63;
    const int quad = lane >> 4, l16 = lane & 15;
    const int p0 = blockIdx.x * 128 + wave * 32;

    // Stage chunk 0 (async DMA, drained by the barrier below).
    #pragma unroll
    for (int it = 0; it < 9; it++) {
        int off = (it * 4 + wave) * 512;             // ushort offset, 1KB/wave/iter
        __builtin_amdgcn_global_load_lds(
            (const __attribute__((address_space(1))) void*)(wbf + off + lane * 8),
            (__attribute__((address_space(3))) void*)(&wc[off]), 16, 0, 0);
    }

    // B-frags: all 192 channels of this wave's 32 tokens, held in VGPRs.
    bf16x8 bfr[2][6];
    #pragma unroll
    for (int nt = 0; nt < 2; nt++) {
        int token = p0 + nt * 16 + l16;
        #pragma unroll
        for (int k = 0; k < 6; k++) {
            if (OCH == 576)   // octet layout
                bfr[nt][k] = *(const bf16x8*)(xin + (size_t)(token >> 6) * 12288
                                              + (k * 4 + quad) * 512 + (token & 63) * 8);
            else              // token-row layout
                bfr[nt][k] = *(const bf16x8*)(xin + (size_t)token * CCH + k * 32 + quad * 8);
        }
    }

    __syncthreads();    // vmcnt(0) drain: chunk 0 + bfr ready

    #pragma unroll
    for (int ch = 0; ch < OCH / 96; ch++) {
        f32x4 acc[6][2];
        #pragma unroll
        for (int m = 0; m < 6; m++)
            #pragma unroll
            for (int nt = 0; nt < 2; nt++) acc[m][nt] = (f32x4){0.f, 0.f, 0.f, 0.f};

        const ushort* wl = wc + (size_t)l16 * 192;
        #pragma unroll
        for (int k = 0; k < 6; k++) {
            const ushort* wk = wl + ((k * 4 + quad) ^ (l16 & 7)) * 8;
            #pragma unroll
            for (int m = 0; m < 6; m++) {
                bf16x8 afrag = *(const bf16x8*)(wk + m * 3072);
                acc[m][0] = __builtin_amdgcn_mfma_f32_16x16x32_bf16(afrag, bfr[0][k], acc[m][0], 0, 0, 0);
                acc[m][1] = __builtin_amdgcn_mfma_f32_16x16x32_bf16(afrag, bfr[1][k], acc[m][1], 0, 0, 0);
            }
        }

        // Issue next chunk's staging now; its latency hides under the epilogue.
        if (ch + 1 < OCH / 96) {
            __syncthreads();     // all waves done reading chunk ch
            const ushort* wsrc = wbf + (size_t)(ch + 1) * (96 * 192);
            #pragma unroll
            for (int it = 0; it < 9; it++) {
                int off = (it * 4 + wave) * 512;
                __builtin_amdgcn_global_load_lds(
                    (const __attribute__((address_space(1))) void*)(wsrc + off + lane * 8),
                    (__attribute__((address_space(3))) void*)(&wc[off]), 16, 0, 0);
            }
        }

        // Epilogue. D row = quad*4+rg (o dim), col = l16 (token dim).
        const int obase = ch * 96;
        #pragma unroll
        for (int m = 0; m < 6; m++) {
            const int o0 = obase + m * 16 + quad * 4;          // %4 == 0
            float4 bb = *(const float4*)(bias + o0);           // 16-lane broadcast, cached
            #pragma unroll
            for (int nt = 0; nt < 2; nt++) {
                int token = p0 + nt * 16 + l16;
                int win = token >> 6, t = token & 63;
                float f0 = acc[m][nt][0] + bb.x, f1 = acc[m][nt][1] + bb.y;
                float f2 = acc[m][nt][2] + bb.z, f3 = acc[m][nt][3] + bb.w;
                if (OCH == 576) {
                    const int s = o0 / 192;                    // uniform per (ch,m)
                    const int rem = o0 % 192;
                    const int h = rem >> 5, d0 = rem & 31;     // d0 %4 == 0
                    size_t wh = (size_t)win * 6 + h;
                    if (s == 2) {
                        vto[(wh * 32 + d0 + 0) * 64 + t] = f2bf(f0);
                        vto[(wh * 32 + d0 + 1) * 64 + t] = f2bf(f1);
                        vto[(wh * 32 + d0 + 2) * 64 + t] = f2bf(f2);
                        vto[(wh * 32 + d0 + 3) * 64 + t] = f2bf(f3);
                    } else {
                        uint2 pk;
                        pk.x = pk2(f0, f1);
                        pk.y = pk2(f2, f3);
                        ushort* dst = (s == 0 ? qo : ko) + (wh * 64 + t) * 32 + d0;
                        *(uint2*)dst = pk;
                    }
                } else {
                    int b = win / 784, hn = (win / 28) % 28, wn = win % 28;
                    int hh = (hn * 8 + (t >> 3) + SHIFT) % HHW;
                    int ww = (wn * 8 + (t & 7) + SHIFT) % HHW;
                    float* dst = dout + ((size_t)(b * CCH + o0) * HHW + hh) * HHW + ww;
                    dst[0] = f0; dst[(size_t)HHW * HHW] = f1;
                    dst[2 * (size_t)HHW * HHW] = f2; dst[3 * (size_t)HHW * HHW] = f3;
                }
            }
        }
        if (ch + 1 < OCH / 96) __syncthreads();   // staging DMA drained (vmcnt 0)
    }
}

// ---------------------------------------------------------------------------
// attn: one block = one window, 6 waves = 6 heads. QK^T -> softmax -> P via
// LDS -> PV. Output X2 bf16 [t][c] ALIASED onto the Q buffer (same per-window
// 24 KB block). Safe: all Q/K/V frag loads are issued before __syncthreads
// (which drains vmcnt(0)); X2 stores happen strictly after.
// ---------------------------------------------------------------------------
__global__ __launch_bounds__(384, 3) void attn_win(
    ushort* qx2,                                   // Q in / X2 out (aliased)
    const ushort* __restrict__ k, const ushort* __restrict__ vt)
{
    __shared__ ushort pt[6][64][72];

    const int tid = threadIdx.x;
    const int h = tid >> 6, lane = tid & 63;
    const int quad = lane >> 4, l16 = lane & 15;
    const int win = blockIdx.x;

    const ushort* qp = qx2 + (size_t)(win * 6 + h) * 2048;
    const ushort* kp = k   + (size_t)(win * 6 + h) * 2048;
    const ushort* vp = vt  + (size_t)(win * 6 + h) * 2048;

    // Hoist K and V frags (V must be loaded before the barrier for aliasing).
    bf16x8 kf[4], vf[2][2];
    #pragma unroll
    for (int nt = 0; nt < 4; nt++) kf[nt] = *(const bf16x8*)&kp[(nt * 16 + l16) * 32 + quad * 8];
    #pragma unroll
    for (int ks = 0; ks < 2; ks++)
        #pragma unroll
        for (int nt = 0; nt < 2; nt++)
            vf[ks][nt] = *(const bf16x8*)&vp[(nt * 16 + l16) * 64 + ks * 32 + quad * 8];

    f32x4 s[4][4];
    #pragma unroll
    for (int mt = 0; mt < 4; mt++) {
        bf16x8 qf = *(const bf16x8*)&qp[(mt * 16 + l16) * 32 + quad * 8];
        #pragma unroll
        for (int nt = 0; nt < 4; nt++) {
            s[mt][nt] = (f32x4){0.f, 0.f, 0.f, 0.f};
            s[mt][nt] = __builtin_amdgcn_mfma_f32_16x16x32_bf16(qf, kf[nt], s[mt][nt], 0, 0, 0);
        }
    }

    const float SC = 0.25506953149031837f;   // (1/sqrt(32)) * log2(e)
    #pragma unroll
    for (int mt = 0; mt < 4; mt++) {
        #pragma unroll
        for (int rg = 0; rg < 4; rg++) {
            float v0 = s[mt][0][rg], v1 = s[mt][1][rg], v2 = s[mt][2][rg], v3 = s[mt][3][rg];
            float mx = fmaxf(fmaxf(v0, v1), fmaxf(v2, v3));
            #pragma unroll
            for (int msk = 1; msk < 16; msk <<= 1) mx = fmaxf(mx, __shfl_xor(mx, msk, 64));
            float e0 = exp2f((v0 - mx) * SC), e1 = exp2f((v1 - mx) * SC);
            float e2 = exp2f((v2 - mx) * SC), e3 = exp2f((v3 - mx) * SC);
            float sm = (e0 + e1) + (e2 + e3);
            #pragma unroll
            for (int msk = 1; msk < 16; msk <<= 1) sm += __shfl_xor(sm, msk, 64);
            float r = __builtin_amdgcn_rcpf(sm);
            int qt = mt * 16 + quad * 4 + rg;
            pt[h][qt][ 0 + l16] = f2bf(e0 * r);
            pt[h][qt][16 + l16] = f2bf(e1 * r);
            pt[h][qt][32 + l16] = f2bf(e2 * r);
            pt[h][qt][48 + l16] = f2bf(e3 * r);
        }
    }
    __syncthreads();   // drains all global loads; X2 stores are after this

    f32x4 o[4][2];
    #pragma unroll
    for (int mt = 0; mt < 4; mt++)
        #pragma unroll
        for (int nt = 0; nt < 2; nt++) o[mt][nt] = (f32x4){0.f, 0.f, 0.f, 0.f};
    #pragma unroll
    for (int ks = 0; ks < 2; ks++)
        #pragma unroll
        for (int mt = 0; mt < 4; mt++) {
            bf16x8 pf = *(const bf16x8*)&pt[h][mt * 16 + l16][ks * 32 + quad * 8];
            #pragma unroll
            for (int nt = 0; nt < 2; nt++)
                o[mt][nt] = __builtin_amdgcn_mfma_f32_16x16x32_bf16(pf, vf[ks][nt], o[mt][nt], 0, 0, 0);
        }

    // X2[t][c] bf16, c = h*32 + nt*16 + l16 (lane-contiguous 32B segments).
    ushort* x2 = qx2 + (size_t)win * 12288;
    #pragma unroll
    for (int mt = 0; mt < 4; mt++)
        #pragma unroll
        for (int nt = 0; nt < 2; nt++)
            #pragma unroll
            for (int rg = 0; rg < 4; rg++) {
                int qt = mt * 16 + quad * 4 + rg;
                x2[qt * CCH + h * 32 + nt * 16 + l16] = f2bf(o[mt][nt][rg]);
            }
}

extern "C" void kernel_launch(void* const* d_in, const int* in_sizes, int n_in,
                              void* d_out, int out_size, void* d_ws, size_t ws_size,
                              hipStream_t stream) {
    const float* x      = (const float*)d_in[0];
    const float* w_qkv  = (const float*)d_in[1];
    const float* b_qkv  = (const float*)d_in[2];
    const float* w_proj = (const float*)d_in[3];
    const float* b_proj = (const float*)d_in[4];
    float* out = (float*)d_out;
    ushort* ws = (ushort*)d_ws;

    ushort* X1 = (ushort*)d_out;       // 77 MB bf16 region inside d_out (154 MB)
    ushort* WQ = (ushort*)d_out + QN;  // bf16 qkv weights in d_out's spare half
                                       // (dead until final gemm writes out)
    ushort* Q  = ws;                   // [win][h][64][32] bf16; becomes X2 [win][t][c]
    ushort* K  = ws + QN;
    ushort* VT = ws + 2 * QN;          // [win][h][32][64] bf16 (ws total 231 MB)
    ushort* WP = VT;                   // bf16 proj weights reuse VT (dead post-attn)

    prep_w       <<<54, 256, 0, stream>>>(w_qkv, WQ, 576);
    prep_x       <<<4 * 28 * 24, 256, 0, stream>>>(x, X1);
    gemm_win<576><<<NTOK / 128, 256, 0, stream>>>(X1, WQ, b_qkv, Q, K, VT, nullptr);
    attn_win     <<<NWIN, 384, 0, stream>>>(Q, K, VT);
    prep_w       <<<18, 256, 0, stream>>>(w_proj, WP, 192);
    gemm_win<192><<<NTOK / 128, 256, 0, stream>>>(Q, WP, b_proj, nullptr, nullptr, nullptr, out);
}

// Round 3
// 514.209 us; speedup vs baseline: 1.4252x; 1.0983x over previous
//
#include <hip/hip_runtime.h>
#include <stdint.h>

// B=4, C=192, H=W=224, WS=8, NH=6, hd=32, SHIFT=4. I/O fp32; internal bf16 MFMA.
#define HHW   224
#define CCH   192
#define SHIFT 4
#define NWIN  3136           // 4 * 28 * 28
#define NTOK  200704         // NWIN * 64
#define QN    38535168ull    // NWIN*6*64*32 elements per Q/K/VT tensor (bf16)

typedef __attribute__((ext_vector_type(8))) short bf16x8;   // MFMA A/B frag
typedef __attribute__((ext_vector_type(4))) float f32x4;    // MFMA C/D frag

__device__ __forceinline__ ushort f2bf(float f) {
    union { float f; uint32_t i; } v; v.f = f;
    uint32_t u = v.i;
    return (ushort)((u + 0x7FFFu + ((u >> 16) & 1u)) >> 16);  // RNE
}
__device__ __forceinline__ uint32_t pk2(float a, float b) {
    return (uint32_t)f2bf(a) | ((uint32_t)f2bf(b) << 16);
}

// ---------------------------------------------------------------------------
// prep_w: weights fp32 [o][c] -> bf16 pre-swizzled linear image, once.
// Image[rg][p*8+j] = w[rg][(p^(rg&7))*8+j]; gemm stages linearly via
// global_load_lds and reads slot p = s_log ^ (l16&7) -> XOR cancels ->
// conflict-free b128 reads.
// ---------------------------------------------------------------------------
__global__ __launch_bounds__(256) void prep_w(const float* __restrict__ w,
                                              ushort* __restrict__ wo, int nrow)
{
    int idx = blockIdx.x * 256 + threadIdx.x;
    if (idx >= nrow * 24) return;
    int rg = idx / 24, p = idx % 24;
    int s = p ^ (rg & 7);                    // XOR only touches low 3 bits
    const float* src = w + (size_t)rg * 192 + s * 8;
    float4 a = *(const float4*)src;
    float4 b = *(const float4*)(src + 4);
    uint4 o;
    o.x = pk2(a.x, a.y); o.y = pk2(a.z, a.w);
    o.z = pk2(b.x, b.y); o.w = pk2(b.z, b.w);
    *(uint4*)(wo + (size_t)rg * 192 + p * 8) = o;
}

// ---------------------------------------------------------------------------
// prep_x: x fp32 [b][c][h][w] -> X1 bf16 [win][oct][t][8ch], roll(+4) folded.
// Block = (b, hn, channel-octet). Reads FULL 896B image rows (zero over-fetch).
// Register transpose -> b128 LDS writes into XOR-swizzled [p][8ch] tile.
// Output: per (window, octet) a 1KB fully-contiguous burst.
// ---------------------------------------------------------------------------
__global__ __launch_bounds__(256) void prep_x(const float* __restrict__ x,
                                              ushort* __restrict__ xo)
{
    __shared__ ushort lt[1792 * 8];          // [p][8ch], 16B rows, swizzled
    const int blk = blockIdx.x;              // ((b*28 + hn)*24 + oct)
    const int oct = blk % 24;
    const int bh  = blk / 24;                // b*28 + hn
    const int hn  = bh % 28;
    const float* xb = x + ((size_t)(bh / 28) * CCH + oct * 8) * (HHW * HHW);

    // Read phase: task u = pixel-quad index (r = u/56, 4-col group q = u%56).
    for (int u = threadIdx.x; u < 448; u += 256) {
        int r = u / 56, q = u % 56;
        int hh = (hn * 8 + r + SHIFT) % HHW;
        int ww = (q * 4 + SHIFT) % HHW;      // %4==0, wrap lands on float4 bound
        const float* src = xb + (size_t)hh * HHW + ww;
        float4 v[8];
        #pragma unroll
        for (int c = 0; c < 8; c++)
            v[c] = *(const float4*)(src + (size_t)c * (HHW * HHW));
        #pragma unroll
        for (int i = 0; i < 4; i++) {
            int p = u * 4 + i;               // = r*224 + q*4 + i
            int sw = p ^ ((p >> 3) & 7);
            uint4 o;
            o.x = pk2(((const float*)&v[0])[i], ((const float*)&v[1])[i]);
            o.y = pk2(((const float*)&v[2])[i], ((const float*)&v[3])[i]);
            o.z = pk2(((const float*)&v[4])[i], ((const float*)&v[5])[i]);
            o.w = pk2(((const float*)&v[6])[i], ((const float*)&v[7])[i]);
            *(uint4*)&lt[sw * 8] = o;
        }
    }
    __syncthreads();

    // Write phase: per window wn, token t -> 16B; lanes t consecutive -> 1KB bursts.
    for (int u = threadIdx.x; u < 1792; u += 256) {
        int wn = u >> 6, t = u & 63;
        int p = (t >> 3) * 224 + wn * 8 + (t & 7);
        int sw = p ^ ((p >> 3) & 7);
        *(uint4*)(xo + (size_t)(bh * 28 + wn) * 12288 + oct * 512 + t * 8) =
            *(const uint4*)&lt[sw * 8];
    }
}

// ---------------------------------------------------------------------------
// GEMM: out[o][p] = bias[o] + sum_c W[o][c] * X1[p][c].  N=128 tokens/block,
// wave owns 32 tokens (2 n-frags); B-frags loaded ONCE directly from global.
// OCH=576 input layout: [win][oct][t][8ch] (fully coalesced 16B/lane).
// OCH=192 input layout: [t][c] token rows (X2 from attn).
// A = pre-converted bf16 weights staged per 96-row chunk via global_load_lds
// (9 x 16B per thread, linear LDS), read back with XOR-swizzled conflict-free
// ds_read_b128. Next chunk's staging is issued before this chunk's epilogue.
// ---------------------------------------------------------------------------
template<int OCH>
__global__ __launch_bounds__(256, 3) void gemm_win(
    const ushort* __restrict__ xin, const ushort* __restrict__ wbf,
    const float* __restrict__ bias,
    ushort* __restrict__ qo, ushort* __restrict__ ko, ushort* __restrict__ vto,
    float* __restrict__ dout)
{
    __shared__ ushort wc[96 * 192];  // 36864 B linear weight chunk (bf16)

    const int tid = threadIdx.x;
    const int wave = tid >> 6, lane = tid & 63;
    const int quad = lane >> 4, l16 = lane & 15;
    const int p0 = blockIdx.x * 128 + wave * 32;

    // Stage chunk 0 (async DMA, drained by the barrier below).
    #pragma unroll
    for (int it = 0; it < 9; it++) {
        int off = (it * 4 + wave) * 512;             // ushort offset, 1KB/wave/iter
        __builtin_amdgcn_global_load_lds(
            (const __attribute__((address_space(1))) void*)(wbf + off + lane * 8),
            (__attribute__((address_space(3))) void*)(&wc[off]), 16, 0, 0);
    }

    // B-frags: all 192 channels of this wave's 32 tokens, held in VGPRs.
    bf16x8 bfr[2][6];
    #pragma unroll
    for (int nt = 0; nt < 2; nt++) {
        int token = p0 + nt * 16 + l16;
        #pragma unroll
        for (int k = 0; k < 6; k++) {
            if (OCH == 576)   // octet layout
                bfr[nt][k] = *(const bf16x8*)(xin + (size_t)(token >> 6) * 12288
                                              + (k * 4 + quad) * 512 + (token & 63) * 8);
            else              // token-row layout
                bfr[nt][k] = *(const bf16x8*)(xin + (size_t)token * CCH + k * 32 + quad * 8);
        }
    }

    __syncthreads();    // vmcnt(0) drain: chunk 0 + bfr ready

    #pragma unroll
    for (int ch = 0; ch < OCH / 96; ch++) {
        f32x4 acc[6][2];
        #pragma unroll
        for (int m = 0; m < 6; m++)
            #pragma unroll
            for (int nt = 0; nt < 2; nt++) acc[m][nt] = (f32x4){0.f, 0.f, 0.f, 0.f};

        const ushort* wl = wc + (size_t)l16 * 192;
        #pragma unroll
        for (int k = 0; k < 6; k++) {
            const ushort* wk = wl + ((k * 4 + quad) ^ (l16 & 7)) * 8;
            #pragma unroll
            for (int m = 0; m < 6; m++) {
                bf16x8 afrag = *(const bf16x8*)(wk + m * 3072);
                acc[m][0] = __builtin_amdgcn_mfma_f32_16x16x32_bf16(afrag, bfr[0][k], acc[m][0], 0, 0, 0);
                acc[m][1] = __builtin_amdgcn_mfma_f32_16x16x32_bf16(afrag, bfr[1][k], acc[m][1], 0, 0, 0);
            }
        }

        // Issue next chunk's staging now; its latency hides under the epilogue.
        if (ch + 1 < OCH / 96) {
            __syncthreads();     // all waves done reading chunk ch
            const ushort* wsrc = wbf + (size_t)(ch + 1) * (96 * 192);
            #pragma unroll
            for (int it = 0; it < 9; it++) {
                int off = (it * 4 + wave) * 512;
                __builtin_amdgcn_global_load_lds(
                    (const __attribute__((address_space(1))) void*)(wsrc + off + lane * 8),
                    (__attribute__((address_space(3))) void*)(&wc[off]), 16, 0, 0);
            }
        }

        // Epilogue. D row = quad*4+rg (o dim), col = l16 (token dim).
        const int obase = ch * 96;
        #pragma unroll
        for (int m = 0; m < 6; m++) {
            const int o0 = obase + m * 16 + quad * 4;          // %4 == 0
            float4 bb = *(const float4*)(bias + o0);           // 16-lane broadcast, cached
            #pragma unroll
            for (int nt = 0; nt < 2; nt++) {
                int token = p0 + nt * 16 + l16;
                int win = token >> 6, t = token & 63;
                float f0 = acc[m][nt][0] + bb.x, f1 = acc[m][nt][1] + bb.y;
                float f2 = acc[m][nt][2] + bb.z, f3 = acc[m][nt][3] + bb.w;
                if (OCH == 576) {
                    const int s = o0 / 192;                    // uniform per (ch,m)
                    const int rem = o0 % 192;
                    const int h = rem >> 5, d0 = rem & 31;     // d0 %4 == 0
                    size_t wh = (size_t)win * 6 + h;
                    if (s == 2) {
                        vto[(wh * 32 + d0 + 0) * 64 + t] = f2bf(f0);
                        vto[(wh * 32 + d0 + 1) * 64 + t] = f2bf(f1);
                        vto[(wh * 32 + d0 + 2) * 64 + t] = f2bf(f2);
                        vto[(wh * 32 + d0 + 3) * 64 + t] = f2bf(f3);
                    } else {
                        uint2 pk;
                        pk.x = pk2(f0, f1);
                        pk.y = pk2(f2, f3);
                        ushort* dst = (s == 0 ? qo : ko) + (wh * 64 + t) * 32 + d0;
                        *(uint2*)dst = pk;
                    }
                } else {
                    int b = win / 784, hn = (win / 28) % 28, wn = win % 28;
                    int hh = (hn * 8 + (t >> 3) + SHIFT) % HHW;
                    int ww = (wn * 8 + (t & 7) + SHIFT) % HHW;
                    float* dst = dout + ((size_t)(b * CCH + o0) * HHW + hh) * HHW + ww;
                    dst[0] = f0; dst[(size_t)HHW * HHW] = f1;
                    dst[2 * (size_t)HHW * HHW] = f2; dst[3 * (size_t)HHW * HHW] = f3;
                }
            }
        }
        if (ch + 1 < OCH / 96) __syncthreads();   // staging DMA drained (vmcnt 0)
    }
}

// ---------------------------------------------------------------------------
// attn: one block = one window, 6 waves = 6 heads. SWAPPED operands:
//   S^T = mfma(K, Q)  -> lane holds a q-column: 16 k-values locally, the rest
//   in the 3 quad-partner lanes -> softmax = local 16-reduce + 2 shuffles.
//   P stored packed (b64) into XOR-swizzled pt[q][64] (bank-uniform writes
//   AND b128 reads; stride 64 -> LDS 48KB -> 3 blocks/CU).
//   O^T = mfma(V^T, P^T) -> accumulator regs = consecutive channels -> packed
//   uint2 X2 stores.
// X2 bf16 [t][c] ALIASED onto Q. Safe: all Q/K/V loads issue before
// __syncthreads (vmcnt(0) drain); X2 stores strictly after.
// ---------------------------------------------------------------------------
__global__ __launch_bounds__(384, 4) void attn_win(
    ushort* qx2,                                   // Q in / X2 out (aliased)
    const ushort* __restrict__ k, const ushort* __restrict__ vt)
{
    __shared__ ushort pt[6][64 * 64];   // per-head swizzled P [q][k]

    const int tid = threadIdx.x;
    const int h = tid >> 6, lane = tid & 63;
    const int quad = lane >> 4, l16 = lane & 15;
    const int win = blockIdx.x;

    const ushort* qp = qx2 + (size_t)(win * 6 + h) * 2048;
    const ushort* kp = k   + (size_t)(win * 6 + h) * 2048;
    const ushort* vp = vt  + (size_t)(win * 6 + h) * 2048;

    // K rows as A-frags, Q as B-frags, V^T rows as A-frags (all pre-barrier).
    bf16x8 kf[4], qf[4], vf[2][2];
    #pragma unroll
    for (int nt = 0; nt < 4; nt++) kf[nt] = *(const bf16x8*)&kp[(nt * 16 + l16) * 32 + quad * 8];
    #pragma unroll
    for (int nt = 0; nt < 4; nt++) qf[nt] = *(const bf16x8*)&qp[(nt * 16 + l16) * 32 + quad * 8];
    #pragma unroll
    for (int md = 0; md < 2; md++)
        #pragma unroll
        for (int ks = 0; ks < 2; ks++)
            vf[md][ks] = *(const bf16x8*)&vp[(md * 16 + l16) * 64 + ks * 32 + quad * 8];

    const float SC = 0.25506953149031837f;   // (1/sqrt(32)) * log2(e)
    ushort* ph = pt[h];

    // S^T tiles per q-pair: row = k (quad*4+rg), col = q (l16).
    #pragma unroll
    for (int nq = 0; nq < 4; nq += 2) {
        f32x4 sc[2][4];
        #pragma unroll
        for (int j = 0; j < 2; j++)
            #pragma unroll
            for (int mk = 0; mk < 4; mk++) {
                sc[j][mk] = (f32x4){0.f, 0.f, 0.f, 0.f};
                sc[j][mk] = __builtin_amdgcn_mfma_f32_16x16x32_bf16(kf[mk], qf[nq + j], sc[j][mk], 0, 0, 0);
            }
        #pragma unroll
        for (int j = 0; j < 2; j++) {
            float mx = sc[j][0][0];
            #pragma unroll
            for (int mk = 0; mk < 4; mk++)
                #pragma unroll
                for (int rg = 0; rg < 4; rg++) mx = fmaxf(mx, sc[j][mk][rg]);
            mx = fmaxf(mx, __shfl_xor(mx, 16, 64));
            mx = fmaxf(mx, __shfl_xor(mx, 32, 64));
            float e[4][4];
            float sm = 0.f;
            #pragma unroll
            for (int mk = 0; mk < 4; mk++)
                #pragma unroll
                for (int rg = 0; rg < 4; rg++) {
                    e[mk][rg] = exp2f((sc[j][mk][rg] - mx) * SC);
                    sm += e[mk][rg];
                }
            sm += __shfl_xor(sm, 16, 64);
            sm += __shfl_xor(sm, 32, 64);
            float r = __builtin_amdgcn_rcpf(sm);
            const int q = (nq + j) * 16 + l16;
            const int sx = q & 7;
            ushort* row = ph + q * 64;
            #pragma unroll
            for (int mk = 0; mk < 4; mk++) {
                uint2 w;
                w.x = pk2(e[mk][0] * r, e[mk][1] * r);
                w.y = pk2(e[mk][2] * r, e[mk][3] * r);
                int s0 = mk * 2 + (quad >> 1);
                *(uint2*)(row + (((s0 ^ sx) << 3) + (quad & 1) * 4)) = w;
            }
        }
    }
    __syncthreads();   // drains all global loads; X2 stores are after this

    // O^T = V^T (A) x P^T (B from pt): row = d, col = q.
    f32x4 o[2][4];
    #pragma unroll
    for (int md = 0; md < 2; md++)
        #pragma unroll
        for (int nq = 0; nq < 4; nq++) o[md][nq] = (f32x4){0.f, 0.f, 0.f, 0.f};
    #pragma unroll
    for (int ks = 0; ks < 2; ks++)
        #pragma unroll
        for (int nq = 0; nq < 4; nq++) {
            const int q = nq * 16 + l16;
            bf16x8 pf = *(const bf16x8*)(ph + q * 64 + ((((ks * 4 + quad) ^ (q & 7))) << 3));
            #pragma unroll
            for (int md = 0; md < 2; md++)
                o[md][nq] = __builtin_amdgcn_mfma_f32_16x16x32_bf16(vf[md][ks], pf, o[md][nq], 0, 0, 0);
        }

    // X2[t][c] bf16: 4 consecutive channels per acc frag -> packed 8B stores.
    ushort* x2 = qx2 + (size_t)win * 12288;
    #pragma unroll
    for (int md = 0; md < 2; md++)
        #pragma unroll
        for (int nq = 0; nq < 4; nq++) {
            const int q = nq * 16 + l16;
            const int c = h * 32 + md * 16 + quad * 4;
            uint2 w;
            w.x = pk2(o[md][nq][0], o[md][nq][1]);
            w.y = pk2(o[md][nq][2], o[md][nq][3]);
            *(uint2*)(x2 + q * CCH + c) = w;
        }
}

extern "C" void kernel_launch(void* const* d_in, const int* in_sizes, int n_in,
                              void* d_out, int out_size, void* d_ws, size_t ws_size,
                              hipStream_t stream) {
    const float* x      = (const float*)d_in[0];
    const float* w_qkv  = (const float*)d_in[1];
    const float* b_qkv  = (const float*)d_in[2];
    const float* w_proj = (const float*)d_in[3];
    const float* b_proj = (const float*)d_in[4];
    float* out = (float*)d_out;
    ushort* ws = (ushort*)d_ws;

    ushort* X1 = (ushort*)d_out;       // 77 MB bf16 region inside d_out (154 MB)
    ushort* WQ = (ushort*)d_out + QN;  // bf16 qkv weights in d_out's spare half
                                       // (dead until final gemm writes out)
    ushort* Q  = ws;                   // [win][h][64][32] bf16; becomes X2 [win][t][c]
    ushort* K  = ws + QN;
    ushort* VT = ws + 2 * QN;          // [win][h][32][64] bf16 (ws total 231 MB)
    ushort* WP = VT;                   // bf16 proj weights reuse VT (dead post-attn)

    prep_w       <<<54, 256, 0, stream>>>(w_qkv, WQ, 576);
    prep_x       <<<4 * 28 * 24, 256, 0, stream>>>(x, X1);
    gemm_win<576><<<NTOK / 128, 256, 0, stream>>>(X1, WQ, b_qkv, Q, K, VT, nullptr);
    attn_win     <<<NWIN, 384, 0, stream>>>(Q, K, VT);
    prep_w       <<<18, 256, 0, stream>>>(w_proj, WP, 192);
    gemm_win<192><<<NTOK / 128, 256, 0, stream>>>(Q, WP, b_proj, nullptr, nullptr, nullptr, out);
}